// Round 1
// baseline (829.403 us; speedup 1.0000x reference)
//
#include <hip/hip_runtime.h>
#include <math.h>

// Problem constants (B=8, C=512, H=W=64)
constexpr int CB = 8;
constexpr int CC = 512;
constexpr int CN = 4096;   // H*W
constexpr int CM = 1024;   // pooled positions
constexpr int C8 = 64;     // C/8
constexpr int C2 = 256;    // C/2

// ---------------------------------------------------------------------------
// Projection GEMM: Y[b,oc,pos] = sum_k W[oc,k] * X[b,k,pos]
// MODE 0: write Y[b][oc][pos] (row-major, OC param)
// MODE 1: write transposed thetaT[b][pos][oc]  (OC must be 64)
// Block: 256 threads, 64x64 output tile, K staged in 16-chunks.
// ---------------------------------------------------------------------------
template<int MODE>
__global__ __launch_bounds__(256)
void proj_gemm(const float* __restrict__ W, const float* __restrict__ X,
               float* __restrict__ Y, int OC) {
  __shared__ __align__(16) float As[16][68];  // As[k][oc_local], padded
  __shared__ __align__(16) float Bs[16][64];  // Bs[k][pos_local]
  const int b = blockIdx.z;
  const int oc0 = blockIdx.y * 64;
  const int pos0 = blockIdx.x * 64;
  const float* Xb = X + (size_t)b * CC * CN;
  const int tid = threadIdx.x;
  const int tx = tid & 15, ty = tid >> 4;
  float acc[4][4] = {};
  for (int k0 = 0; k0 < CC; k0 += 16) {
#pragma unroll
    for (int it = 0; it < 4; ++it) {
      int r = ty + it * 16;
      As[tx][r] = W[(size_t)(oc0 + r) * CC + k0 + tx];
    }
#pragma unroll
    for (int it = 0; it < 4; ++it) {
      int k = (tid >> 6) + it * 4;
      int p = tid & 63;
      Bs[k][p] = Xb[(size_t)(k0 + k) * CN + pos0 + p];
    }
    __syncthreads();
#pragma unroll
    for (int k = 0; k < 16; ++k) {
      const float4 a4 = *(const float4*)&As[k][ty * 4];
      const float4 b4 = *(const float4*)&Bs[k][tx * 4];
      const float av[4] = {a4.x, a4.y, a4.z, a4.w};
      const float bv[4] = {b4.x, b4.y, b4.z, b4.w};
#pragma unroll
      for (int i = 0; i < 4; ++i)
#pragma unroll
        for (int j = 0; j < 4; ++j)
          acc[i][j] = fmaf(av[i], bv[j], acc[i][j]);
    }
    __syncthreads();
  }
  if (MODE == 0) {
    float* Yb = Y + (size_t)b * OC * CN;
#pragma unroll
    for (int i = 0; i < 4; ++i) {
      float4 v = {acc[i][0], acc[i][1], acc[i][2], acc[i][3]};
      *(float4*)&Yb[(size_t)(oc0 + ty * 4 + i) * CN + pos0 + tx * 4] = v;
    }
  } else {
    // thetaT[b][pos][oc], OC == 64
    float* Yb = Y + (size_t)b * CN * C8;
#pragma unroll
    for (int j = 0; j < 4; ++j) {
      float4 v = {acc[0][j], acc[1][j], acc[2][j], acc[3][j]};
      *(float4*)&Yb[(size_t)(pos0 + tx * 4 + j) * C8 + oc0 + ty * 4] = v;
    }
  }
}

// ---------------------------------------------------------------------------
// 2x2 maxpool, phi variant: pre[b,c,pos] -> phi[b,c,p]   (c=64 channels)
// grid: (h2=32, cTile=2, b=8)
// ---------------------------------------------------------------------------
__global__ __launch_bounds__(256)
void pool_phi_k(const float* __restrict__ pre, float* __restrict__ phi) {
  __shared__ float raw[32][129];  // [channel][2 spatial rows = 128 cols], padded
  const int b = blockIdx.z, c0 = blockIdx.y * 32, h2 = blockIdx.x;
  const float* p = pre + ((size_t)b * C8 + c0) * CN + h2 * 128;
  const int tid = threadIdx.x;
#pragma unroll
  for (int it = 0; it < 16; ++it) {
    int e = tid + 256 * it;        // 0..4095 = 32 ch x 128 cols
    int r = e >> 7, col = e & 127;
    raw[r][col] = p[(size_t)r * CN + col];
  }
  __syncthreads();
  float* out = phi + ((size_t)b * C8 + c0) * CM + h2 * 32;
#pragma unroll
  for (int it = 0; it < 4; ++it) {
    int e = tid + 256 * it;        // 0..1023 = 32 ch x 32 w2
    int w2 = e & 31, r = e >> 5;
    float v = fmaxf(fmaxf(raw[r][2 * w2], raw[r][2 * w2 + 1]),
                    fmaxf(raw[r][64 + 2 * w2], raw[r][65 + 2 * w2]));
    out[(size_t)r * CM + w2] = v;
  }
}

// ---------------------------------------------------------------------------
// 2x2 maxpool + transpose, g variant: pre[b,c2,pos] -> gT[b,p,c2]
// grid: (h2=32, cTile=8, b=8)
// ---------------------------------------------------------------------------
__global__ __launch_bounds__(256)
void pool_g_k(const float* __restrict__ pre, float* __restrict__ gT) {
  __shared__ float raw[32][129];
  const int b = blockIdx.z, c0 = blockIdx.y * 32, h2 = blockIdx.x;
  const float* p = pre + ((size_t)b * C2 + c0) * CN + h2 * 128;
  const int tid = threadIdx.x;
#pragma unroll
  for (int it = 0; it < 16; ++it) {
    int e = tid + 256 * it;
    int r = e >> 7, col = e & 127;
    raw[r][col] = p[(size_t)r * CN + col];
  }
  __syncthreads();
  float* out = gT + (size_t)b * CM * C2 + (size_t)(h2 * 32) * C2 + c0;
#pragma unroll
  for (int it = 0; it < 4; ++it) {
    int e = tid + 256 * it;        // r (channel) fastest -> coalesced writes
    int r = e & 31, w2 = e >> 5;
    float v = fmaxf(fmaxf(raw[r][2 * w2], raw[r][2 * w2 + 1]),
                    fmaxf(raw[r][64 + 2 * w2], raw[r][65 + 2 * w2]));
    out[(size_t)w2 * C2 + r] = v;
  }
}

// ---------------------------------------------------------------------------
// Fused attention: per block = (batch b, 32 queries).
// Streams m=1024 keys in 64-wide chunks; exp(scores) -> LDS (transposed);
// accumulates unnormalized P @ gT and the softmax denominator in registers.
// No max-subtraction: logits bounded (~|s|<60), exp and sums fit fp32 easily.
// att[b][q][c2]
// ---------------------------------------------------------------------------
__global__ __launch_bounds__(256)
void attn_kernel(const float* __restrict__ thetaT, const float* __restrict__ phi,
                 const float* __restrict__ gT, float* __restrict__ att) {
  __shared__ __align__(16) float th[32][64];     // [q_local][c]
  __shared__ __align__(16) float scT[64][36];    // [j_local][q_local], padded
  const int b = blockIdx.y;
  const int q0 = blockIdx.x * 32;
  const int tid = threadIdx.x;
  const float* thSrc = thetaT + ((size_t)b * CN + q0) * C8;
#pragma unroll
  for (int it = 0; it < 8; ++it) {
    int e = tid + 256 * it;        // 2048 = 32 x 64
    th[e >> 6][e & 63] = thSrc[e];
  }
  __syncthreads();
  const int tx = tid & 31, ty = tid >> 5;  // att phase: q = ty*4+i, c2 = tx*8+k
  const int qg = tid >> 4;                 // score phase: q in {2qg, 2qg+1}
  const int jg = tid & 15;                 // score phase: j in jg*4..+3
  float acc[4][8] = {};
  float dn[4] = {0.f, 0.f, 0.f, 0.f};
  const float* phiB = phi + (size_t)b * C8 * CM;
  const float* gB = gT + (size_t)b * CM * C2;
  for (int j0 = 0; j0 < CM; j0 += 64) {
    // --- scores for this chunk: s[qq][jj], 2 queries x 4 keys per thread ---
    float s[2][4] = {};
#pragma unroll 4
    for (int c4 = 0; c4 < 16; ++c4) {
      const float4 t0 = *(const float4*)&th[qg * 2][c4 * 4];
      const float4 t1 = *(const float4*)&th[qg * 2 + 1][c4 * 4];
      const float ta[2][4] = {{t0.x, t0.y, t0.z, t0.w},
                              {t1.x, t1.y, t1.z, t1.w}};
#pragma unroll
      for (int cc = 0; cc < 4; ++cc) {
        const int c = c4 * 4 + cc;
        const float4 pv = *(const float4*)&phiB[(size_t)c * CM + j0 + jg * 4];
#pragma unroll
        for (int qq = 0; qq < 2; ++qq) {
          s[qq][0] = fmaf(ta[qq][cc], pv.x, s[qq][0]);
          s[qq][1] = fmaf(ta[qq][cc], pv.y, s[qq][1]);
          s[qq][2] = fmaf(ta[qq][cc], pv.z, s[qq][2]);
          s[qq][3] = fmaf(ta[qq][cc], pv.w, s[qq][3]);
        }
      }
    }
    __syncthreads();  // previous chunk's scT reads complete
#pragma unroll
    for (int qq = 0; qq < 2; ++qq)
#pragma unroll
      for (int jj = 0; jj < 4; ++jj)
        scT[jg * 4 + jj][qg * 2 + qq] = __expf(s[qq][jj]);
    __syncthreads();  // scT visible
    // --- accumulate P @ gT + denominator ---
#pragma unroll 2
    for (int jl = 0; jl < 64; ++jl) {
      const float4 p4 = *(const float4*)&scT[jl][ty * 4];
      const float* gRow = gB + (size_t)(j0 + jl) * C2 + tx * 8;
      const float4 g0 = *(const float4*)&gRow[0];
      const float4 g1 = *(const float4*)&gRow[4];
      dn[0] += p4.x; dn[1] += p4.y; dn[2] += p4.z; dn[3] += p4.w;
      const float pvv[4] = {p4.x, p4.y, p4.z, p4.w};
      const float gvv[8] = {g0.x, g0.y, g0.z, g0.w, g1.x, g1.y, g1.z, g1.w};
#pragma unroll
      for (int i = 0; i < 4; ++i)
#pragma unroll
        for (int k = 0; k < 8; ++k)
          acc[i][k] = fmaf(pvv[i], gvv[k], acc[i][k]);
    }
    __syncthreads();  // done reading scT before next chunk overwrites
  }
  float* attB = att + ((size_t)b * CN + q0) * C2;
#pragma unroll
  for (int i = 0; i < 4; ++i) {
    const int q = ty * 4 + i;
    const float inv = 1.0f / dn[i];
    float4 o0 = {acc[i][0] * inv, acc[i][1] * inv, acc[i][2] * inv, acc[i][3] * inv};
    float4 o1 = {acc[i][4] * inv, acc[i][5] * inv, acc[i][6] * inv, acc[i][7] * inv};
    float4* dst = (float4*)&attB[(size_t)q * C2 + tx * 8];
    dst[0] = o0;
    dst[1] = o1;
  }
}

// ---------------------------------------------------------------------------
// Output projection + residual: out[b,c,pos] = x[b,c,pos] + gamma *
//    sum_k w_o[c,k] * att[b,pos,k]        (K = 256)
// ---------------------------------------------------------------------------
__global__ __launch_bounds__(256)
void oproj_kernel(const float* __restrict__ Wo, const float* __restrict__ attv,
                  const float* __restrict__ X, const float* __restrict__ gamma,
                  float* __restrict__ out) {
  __shared__ __align__(16) float As[16][68];  // As[k][c_local]
  __shared__ __align__(16) float Bs[16][68];  // Bs[k][pos_local]
  const int b = blockIdx.z;
  const int c0 = blockIdx.y * 64;
  const int pos0 = blockIdx.x * 64;
  const float* attB = attv + (size_t)b * CN * C2;
  const int tid = threadIdx.x;
  const int tx = tid & 15, ty = tid >> 4;
  float acc[4][4] = {};
  for (int k0 = 0; k0 < C2; k0 += 16) {
#pragma unroll
    for (int it = 0; it < 4; ++it) {
      int r = ty + it * 16;
      As[tx][r] = Wo[(size_t)(c0 + r) * C2 + k0 + tx];
      Bs[tx][r] = attB[(size_t)(pos0 + r) * C2 + k0 + tx];
    }
    __syncthreads();
#pragma unroll
    for (int k = 0; k < 16; ++k) {
      const float4 a4 = *(const float4*)&As[k][ty * 4];
      const float4 b4 = *(const float4*)&Bs[k][tx * 4];
      const float av[4] = {a4.x, a4.y, a4.z, a4.w};
      const float bv[4] = {b4.x, b4.y, b4.z, b4.w};
#pragma unroll
      for (int i = 0; i < 4; ++i)
#pragma unroll
        for (int j = 0; j < 4; ++j)
          acc[i][j] = fmaf(av[i], bv[j], acc[i][j]);
    }
    __syncthreads();
  }
  const float gm = gamma[0];
  const float* Xb = X + (size_t)b * CC * CN;
  float* outB = out + (size_t)b * CC * CN;
#pragma unroll
  for (int i = 0; i < 4; ++i) {
    const size_t row = (size_t)(c0 + ty * 4 + i) * CN + pos0 + tx * 4;
    const float4 xv = *(const float4*)&Xb[row];
    float4 v = {xv.x + gm * acc[i][0], xv.y + gm * acc[i][1],
                xv.z + gm * acc[i][2], xv.w + gm * acc[i][3]};
    *(float4*)&outB[row] = v;
  }
}

// ---------------------------------------------------------------------------
extern "C" void kernel_launch(void* const* d_in, const int* in_sizes, int n_in,
                              void* d_out, int out_size, void* d_ws, size_t ws_size,
                              hipStream_t stream) {
  const float* x       = (const float*)d_in[0];
  const float* w_theta = (const float*)d_in[1];
  const float* w_phi   = (const float*)d_in[2];
  const float* w_g     = (const float*)d_in[3];
  const float* w_g_o   = (const float*)d_in[4];
  const float* gamma   = (const float*)d_in[5];
  float* out = (float*)d_out;
  float* ws = (float*)d_ws;

  // Workspace layout (floats). Total = 13,107,200 floats = 50 MiB.
  float* thetaT = ws;                       // [B, N, 64]      2,097,152
  float* phiP   = ws + 2097152;             // [B, 64, M]        524,288
  float* gTP    = ws + 2621440;             // [B, M, 256]     2,097,152
  float* region = ws + 4718592;             // 8,388,608: pre buffers, then att
  float* pre    = region;                   // phi_pre [B,64,N] or g_pre [B,256,N]
  float* attv   = region;                   // att [B, N, 256] (g_pre is dead)

  dim3 blk(256);
  // theta projection (transposed output)
  proj_gemm<1><<<dim3(64, 1, CB), blk, 0, stream>>>(w_theta, x, thetaT, C8);
  // phi projection -> pre, then pool
  proj_gemm<0><<<dim3(64, 1, CB), blk, 0, stream>>>(w_phi, x, pre, C8);
  pool_phi_k<<<dim3(32, 2, CB), blk, 0, stream>>>(pre, phiP);
  // g projection -> pre, then pool+transpose
  proj_gemm<0><<<dim3(64, 4, CB), blk, 0, stream>>>(w_g, x, pre, C2);
  pool_g_k<<<dim3(32, 8, CB), blk, 0, stream>>>(pre, gTP);
  // fused softmax attention -> att (reuses region; g_pre no longer needed)
  attn_kernel<<<dim3(128, CB), blk, 0, stream>>>(thetaT, phiP, gTP, attv);
  // output projection + residual
  oproj_kernel<<<dim3(64, 8, CB), blk, 0, stream>>>(w_g_o, attv, x, gamma, out);
}

// Round 2
// 550.760 us; speedup vs baseline: 1.5059x; 1.5059x over previous
//
#include <hip/hip_runtime.h>
#include <math.h>

// Problem constants (B=8, C=512, H=W=64)
constexpr int CB = 8;
constexpr int CC = 512;
constexpr int CN = 4096;   // H*W
constexpr int CM = 1024;   // pooled positions
constexpr int C8 = 64;     // C/8
constexpr int C2 = 256;    // C/2

typedef __attribute__((ext_vector_type(8))) short bf16x8;
typedef __attribute__((ext_vector_type(4))) float f32x4;

__device__ inline unsigned short f2bf(float f) {
  unsigned int u = __float_as_uint(f);
  return (unsigned short)((u + 0x7FFFu + ((u >> 16) & 1u)) >> 16);
}
__device__ inline float bf2f(unsigned short h) {
  return __uint_as_float(((unsigned int)h) << 16);
}

// ---------------------------------------------------------------------------
// fp32 projection GEMM: Y[b,oc,pos] = sum_k W[oc,k] * X[b,k,pos]  (row-major)
// ---------------------------------------------------------------------------
__global__ __launch_bounds__(256)
void proj_gemm(const float* __restrict__ W, const float* __restrict__ X,
               float* __restrict__ Y, int OC) {
  __shared__ __align__(16) float As[16][68];
  __shared__ __align__(16) float Bs[16][64];
  const int b = blockIdx.z;
  const int oc0 = blockIdx.y * 64;
  const int pos0 = blockIdx.x * 64;
  const float* Xb = X + (size_t)b * CC * CN;
  const int tid = threadIdx.x;
  const int tx = tid & 15, ty = tid >> 4;
  float acc[4][4] = {};
  for (int k0 = 0; k0 < CC; k0 += 16) {
#pragma unroll
    for (int it = 0; it < 4; ++it) {
      int r = ty + it * 16;
      As[tx][r] = W[(size_t)(oc0 + r) * CC + k0 + tx];
    }
#pragma unroll
    for (int it = 0; it < 4; ++it) {
      int k = (tid >> 6) + it * 4;
      int p = tid & 63;
      Bs[k][p] = Xb[(size_t)(k0 + k) * CN + pos0 + p];
    }
    __syncthreads();
#pragma unroll
    for (int k = 0; k < 16; ++k) {
      const float4 a4 = *(const float4*)&As[k][ty * 4];
      const float4 b4 = *(const float4*)&Bs[k][tx * 4];
      const float av[4] = {a4.x, a4.y, a4.z, a4.w};
      const float bv[4] = {b4.x, b4.y, b4.z, b4.w};
#pragma unroll
      for (int i = 0; i < 4; ++i)
#pragma unroll
        for (int j = 0; j < 4; ++j)
          acc[i][j] = fmaf(av[i], bv[j], acc[i][j]);
    }
    __syncthreads();
  }
  float* Yb = Y + (size_t)b * OC * CN;
#pragma unroll
  for (int i = 0; i < 4; ++i) {
    float4 v = {acc[i][0], acc[i][1], acc[i][2], acc[i][3]};
    *(float4*)&Yb[(size_t)(oc0 + ty * 4 + i) * CN + pos0 + tx * 4] = v;
  }
}

// ---------------------------------------------------------------------------
// theta projection -> bf16 hi/lo, transposed: thetaT[b][pos][128] (hi 0..63,
// lo 64..127). Same GEMM core, OC=64.
// ---------------------------------------------------------------------------
__global__ __launch_bounds__(256)
void proj_theta_bf(const float* __restrict__ W, const float* __restrict__ X,
                   unsigned short* __restrict__ thetaT) {
  __shared__ __align__(16) float As[16][68];
  __shared__ __align__(16) float Bs[16][64];
  const int b = blockIdx.z;
  const int pos0 = blockIdx.x * 64;
  const float* Xb = X + (size_t)b * CC * CN;
  const int tid = threadIdx.x;
  const int tx = tid & 15, ty = tid >> 4;
  float acc[4][4] = {};
  for (int k0 = 0; k0 < CC; k0 += 16) {
#pragma unroll
    for (int it = 0; it < 4; ++it) {
      int r = ty + it * 16;
      As[tx][r] = W[(size_t)r * CC + k0 + tx];
    }
#pragma unroll
    for (int it = 0; it < 4; ++it) {
      int k = (tid >> 6) + it * 4;
      int p = tid & 63;
      Bs[k][p] = Xb[(size_t)(k0 + k) * CN + pos0 + p];
    }
    __syncthreads();
#pragma unroll
    for (int k = 0; k < 16; ++k) {
      const float4 a4 = *(const float4*)&As[k][ty * 4];
      const float4 b4 = *(const float4*)&Bs[k][tx * 4];
      const float av[4] = {a4.x, a4.y, a4.z, a4.w};
      const float bv[4] = {b4.x, b4.y, b4.z, b4.w};
#pragma unroll
      for (int i = 0; i < 4; ++i)
#pragma unroll
        for (int j = 0; j < 4; ++j)
          acc[i][j] = fmaf(av[i], bv[j], acc[i][j]);
    }
    __syncthreads();
  }
  unsigned short* Yb = thetaT + (size_t)b * CN * 128;
#pragma unroll
  for (int j = 0; j < 4; ++j) {
    const int pos = pos0 + tx * 4 + j;
    ushort4 hi, lo;
    float a0 = acc[0][j], a1 = acc[1][j], a2 = acc[2][j], a3 = acc[3][j];
    hi.x = f2bf(a0); hi.y = f2bf(a1); hi.z = f2bf(a2); hi.w = f2bf(a3);
    lo.x = f2bf(a0 - bf2f(hi.x)); lo.y = f2bf(a1 - bf2f(hi.y));
    lo.z = f2bf(a2 - bf2f(hi.z)); lo.w = f2bf(a3 - bf2f(hi.w));
    *(ushort4*)&Yb[(size_t)pos * 128 + ty * 4] = hi;
    *(ushort4*)&Yb[(size_t)pos * 128 + 64 + ty * 4] = lo;
  }
}

// ---------------------------------------------------------------------------
// 2x2 maxpool + transpose -> phiT[b][m][128] bf16 (hi|lo).  grid (32,2,8)
// ---------------------------------------------------------------------------
__global__ __launch_bounds__(256)
void pool_phi_k(const float* __restrict__ pre, unsigned short* __restrict__ phiT) {
  __shared__ float raw[32][129];
  const int b = blockIdx.z, c0 = blockIdx.y * 32, h2 = blockIdx.x;
  const float* p = pre + ((size_t)b * C8 + c0) * CN + h2 * 128;
  const int tid = threadIdx.x;
#pragma unroll
  for (int it = 0; it < 16; ++it) {
    int e = tid + 256 * it;
    int r = e >> 7, col = e & 127;
    raw[r][col] = p[(size_t)r * CN + col];
  }
  __syncthreads();
  unsigned short* outB = phiT + ((size_t)b * CM + h2 * 32) * 128;
#pragma unroll
  for (int it = 0; it < 4; ++it) {
    int e = tid + 256 * it;        // 1024 = 32 ch x 32 w2, channel fastest
    int r = e & 31, w2 = e >> 5;
    float v = fmaxf(fmaxf(raw[r][2 * w2], raw[r][2 * w2 + 1]),
                    fmaxf(raw[r][64 + 2 * w2], raw[r][65 + 2 * w2]));
    unsigned short hi = f2bf(v);
    outB[(size_t)w2 * 128 + c0 + r] = hi;
    outB[(size_t)w2 * 128 + 64 + c0 + r] = f2bf(v - bf2f(hi));
  }
}

// ---------------------------------------------------------------------------
// 2x2 maxpool -> g[b][c2][m] bf16 (natural layout).  grid (32,8,8)
// ---------------------------------------------------------------------------
__global__ __launch_bounds__(256)
void pool_g_k(const float* __restrict__ pre, unsigned short* __restrict__ gbf) {
  __shared__ float raw[32][129];
  const int b = blockIdx.z, c0 = blockIdx.y * 32, h2 = blockIdx.x;
  const float* p = pre + ((size_t)b * C2 + c0) * CN + h2 * 128;
  const int tid = threadIdx.x;
#pragma unroll
  for (int it = 0; it < 16; ++it) {
    int e = tid + 256 * it;
    int r = e >> 7, col = e & 127;
    raw[r][col] = p[(size_t)r * CN + col];
  }
  __syncthreads();
#pragma unroll
  for (int it = 0; it < 4; ++it) {
    int e = tid + 256 * it;        // w2 fastest -> coalesced m-dim writes
    int w2 = e & 31, r = e >> 5;
    float v = fmaxf(fmaxf(raw[r][2 * w2], raw[r][2 * w2 + 1]),
                    fmaxf(raw[r][64 + 2 * w2], raw[r][65 + 2 * w2]));
    gbf[((size_t)b * C2 + c0 + r) * CM + h2 * 32 + w2] = f2bf(v);
  }
}

// ---------------------------------------------------------------------------
// MFMA flash attention. Block = (32 queries, batch). 4 waves.
// Wave w: S-subtile (subq=w&1, subj=w>>1); P@g cols [w*64, w*64+64).
// S = th*ph + tl*ph + th*pl  (theta/phi hi-lo split for precision).
// P round-trips LDS in A-frag order; denominator reduced from A-frags.
// att[b][q][c2] fp32.
// ---------------------------------------------------------------------------
__global__ __launch_bounds__(256)
void attn_mfma(const unsigned short* __restrict__ thetaT,
               const unsigned short* __restrict__ phiT,
               const unsigned short* __restrict__ gbf,
               float* __restrict__ att) {
  // [buf][rowtile][kquad][qloc][elem] bf16; A-frag read = 16B contiguous
  __shared__ __align__(16) unsigned short P2[2][2][4][16][8];
  const int b = blockIdx.y;
  const int q0 = blockIdx.x * 32;
  const int tid = threadIdx.x;
  const int w = tid >> 6, l = tid & 63;
  const int l15 = l & 15, quad = l >> 4;
  const int subq = w & 1, subj = w >> 1;

  // preload theta A-frags (hi/lo, 2 K-chunks of 32)
  const unsigned short* trow =
      thetaT + (size_t)(b * CN + q0 + subq * 16 + l15) * 128;
  const bf16x8 ah0 = *(const bf16x8*)(trow + quad * 8);
  const bf16x8 ah1 = *(const bf16x8*)(trow + 32 + quad * 8);
  const bf16x8 al0 = *(const bf16x8*)(trow + 64 + quad * 8);
  const bf16x8 al1 = *(const bf16x8*)(trow + 96 + quad * 8);

  f32x4 acc[2][4] = {};   // [rowtile][coltile]
  float dn0 = 0.f, dn1 = 0.f;
  const unsigned short* phB = phiT + (size_t)b * CM * 128;
  const unsigned short* gB = gbf + (size_t)b * C2 * CM;
  const int jl = subj * 16 + l15;          // j-local within 32-chunk
  const int kq = jl >> 3, el = jl & 7;

  for (int j0 = 0; j0 < CM; j0 += 32) {
    const int buf = (j0 >> 5) & 1;
    // --- scores: 16x16 subtile, K=64 in 2 MFMA chunks x 3 hi/lo terms ---
    const unsigned short* prow = phB + (size_t)(j0 + jl) * 128;
    const bf16x8 bh0 = *(const bf16x8*)(prow + quad * 8);
    const bf16x8 bh1 = *(const bf16x8*)(prow + 32 + quad * 8);
    const bf16x8 bl0 = *(const bf16x8*)(prow + 64 + quad * 8);
    const bf16x8 bl1 = *(const bf16x8*)(prow + 96 + quad * 8);
    f32x4 S = {0.f, 0.f, 0.f, 0.f};
    S = __builtin_amdgcn_mfma_f32_16x16x32_bf16(ah0, bh0, S, 0, 0, 0);
    S = __builtin_amdgcn_mfma_f32_16x16x32_bf16(ah1, bh1, S, 0, 0, 0);
    S = __builtin_amdgcn_mfma_f32_16x16x32_bf16(al0, bh0, S, 0, 0, 0);
    S = __builtin_amdgcn_mfma_f32_16x16x32_bf16(al1, bh1, S, 0, 0, 0);
    S = __builtin_amdgcn_mfma_f32_16x16x32_bf16(ah0, bl0, S, 0, 0, 0);
    S = __builtin_amdgcn_mfma_f32_16x16x32_bf16(ah1, bl1, S, 0, 0, 0);
    // --- exp -> bf16 -> LDS (A-frag order) ---
#pragma unroll
    for (int r = 0; r < 4; ++r)
      P2[buf][subq][kq][quad * 4 + r][el] = f2bf(__expf(S[r]));
    __syncthreads();
    // --- P A-frags + denominator partial ---
    const bf16x8 pa0 = *(const bf16x8*)&P2[buf][0][quad][l15][0];
    const bf16x8 pa1 = *(const bf16x8*)&P2[buf][1][quad][l15][0];
    float s0 = 0.f, s1 = 0.f;
#pragma unroll
    for (int e = 0; e < 8; ++e) {
      s0 += bf2f((unsigned short)pa0[e]);
      s1 += bf2f((unsigned short)pa1[e]);
    }
    s0 += __shfl_xor(s0, 16); s0 += __shfl_xor(s0, 32);
    s1 += __shfl_xor(s1, 16); s1 += __shfl_xor(s1, 32);
    dn0 += s0; dn1 += s1;
    // --- P @ g ---
#pragma unroll
    for (int ct = 0; ct < 4; ++ct) {
      const unsigned short* grow =
          gB + (size_t)(w * 64 + ct * 16 + l15) * CM + j0 + quad * 8;
      const bf16x8 gb = *(const bf16x8*)grow;
      acc[0][ct] = __builtin_amdgcn_mfma_f32_16x16x32_bf16(pa0, gb, acc[0][ct], 0, 0, 0);
      acc[1][ct] = __builtin_amdgcn_mfma_f32_16x16x32_bf16(pa1, gb, acc[1][ct], 0, 0, 0);
    }
  }
  // --- normalize + store ---
  const float inv0 = 1.0f / dn0;   // valid at lane with l15 == row
  const float inv1 = 1.0f / dn1;
  float* attB = att + ((size_t)b * CN + q0) * C2;
#pragma unroll
  for (int r = 0; r < 4; ++r) {
    const int qc = quad * 4 + r;
    const float i0 = __shfl(inv0, qc);
    const float i1 = __shfl(inv1, qc);
#pragma unroll
    for (int ct = 0; ct < 4; ++ct) {
      const int col = w * 64 + ct * 16 + l15;
      attB[(size_t)qc * C2 + col] = acc[0][ct][r] * i0;
      attB[(size_t)(16 + qc) * C2 + col] = acc[1][ct][r] * i1;
    }
  }
}

// ---------------------------------------------------------------------------
// Output projection + residual: out = x + gamma * (w_o @ att)
// ---------------------------------------------------------------------------
__global__ __launch_bounds__(256)
void oproj_kernel(const float* __restrict__ Wo, const float* __restrict__ attv,
                  const float* __restrict__ X, const float* __restrict__ gamma,
                  float* __restrict__ out) {
  __shared__ __align__(16) float As[16][68];
  __shared__ __align__(16) float Bs[16][68];
  const int b = blockIdx.z;
  const int c0 = blockIdx.y * 64;
  const int pos0 = blockIdx.x * 64;
  const float* attB = attv + (size_t)b * CN * C2;
  const int tid = threadIdx.x;
  const int tx = tid & 15, ty = tid >> 4;
  float acc[4][4] = {};
  for (int k0 = 0; k0 < C2; k0 += 16) {
#pragma unroll
    for (int it = 0; it < 4; ++it) {
      int r = ty + it * 16;
      As[tx][r] = Wo[(size_t)(c0 + r) * C2 + k0 + tx];
      Bs[tx][r] = attB[(size_t)(pos0 + r) * C2 + k0 + tx];
    }
    __syncthreads();
#pragma unroll
    for (int k = 0; k < 16; ++k) {
      const float4 a4 = *(const float4*)&As[k][ty * 4];
      const float4 b4 = *(const float4*)&Bs[k][tx * 4];
      const float av[4] = {a4.x, a4.y, a4.z, a4.w};
      const float bv[4] = {b4.x, b4.y, b4.z, b4.w};
#pragma unroll
      for (int i = 0; i < 4; ++i)
#pragma unroll
        for (int j = 0; j < 4; ++j)
          acc[i][j] = fmaf(av[i], bv[j], acc[i][j]);
    }
    __syncthreads();
  }
  const float gm = gamma[0];
  const float* Xb = X + (size_t)b * CC * CN;
  float* outB = out + (size_t)b * CC * CN;
#pragma unroll
  for (int i = 0; i < 4; ++i) {
    const size_t row = (size_t)(c0 + ty * 4 + i) * CN + pos0 + tx * 4;
    const float4 xv = *(const float4*)&Xb[row];
    float4 v = {xv.x + gm * acc[i][0], xv.y + gm * acc[i][1],
                xv.z + gm * acc[i][2], xv.w + gm * acc[i][3]};
    *(float4*)&outB[row] = v;
  }
}

// ---------------------------------------------------------------------------
extern "C" void kernel_launch(void* const* d_in, const int* in_sizes, int n_in,
                              void* d_out, int out_size, void* d_ws, size_t ws_size,
                              hipStream_t stream) {
  const float* x       = (const float*)d_in[0];
  const float* w_theta = (const float*)d_in[1];
  const float* w_phi   = (const float*)d_in[2];
  const float* w_g     = (const float*)d_in[3];
  const float* w_o     = (const float*)d_in[4];
  const float* gamma   = (const float*)d_in[5];
  float* out = (float*)d_out;
  char* wsb = (char*)d_ws;

  // Workspace layout (bytes), total 48,234,496:
  //   [0, 33554432)      fp32 region: pre (phi/g projections), later att[B,N,256]
  //   [33554432, +8MiB)  thetaT bf16 [B,4096,128] (hi|lo)
  //   [41943040, +2MiB)  phiT  bf16 [B,1024,128] (hi|lo)
  //   [44040192, +4MiB)  g     bf16 [B,256,1024]
  float* region = (float*)wsb;
  unsigned short* thetaT = (unsigned short*)(wsb + 33554432);
  unsigned short* phiT   = (unsigned short*)(wsb + 41943040);
  unsigned short* gbf    = (unsigned short*)(wsb + 44040192);

  dim3 blk(256);
  proj_theta_bf<<<dim3(64, 1, CB), blk, 0, stream>>>(w_theta, x, thetaT);
  proj_gemm<<<dim3(64, 1, CB), blk, 0, stream>>>(w_phi, x, region, C8);
  pool_phi_k<<<dim3(32, 2, CB), blk, 0, stream>>>(region, phiT);
  proj_gemm<<<dim3(64, 4, CB), blk, 0, stream>>>(w_g, x, region, C2);
  pool_g_k<<<dim3(32, 8, CB), blk, 0, stream>>>(region, gbf);
  attn_mfma<<<dim3(128, CB), blk, 0, stream>>>(thetaT, phiT, gbf, region);
  oproj_kernel<<<dim3(64, 8, CB), blk, 0, stream>>>(w_o, region, x, gamma, out);
}

// Round 3
// 404.931 us; speedup vs baseline: 2.0483x; 1.3601x over previous
//
#include <hip/hip_runtime.h>
#include <math.h>

// Problem constants (B=8, C=512, H=W=64)
constexpr int CB = 8;
constexpr int CC = 512;
constexpr int CN = 4096;   // H*W
constexpr int CM = 1024;   // pooled positions
constexpr int C8 = 64;     // C/8
constexpr int C2 = 256;    // C/2

typedef __attribute__((ext_vector_type(8))) short bf16x8;
typedef __attribute__((ext_vector_type(4))) short bf16x4;
typedef __attribute__((ext_vector_type(4))) float f32x4;

__device__ inline unsigned short f2bf(float f) {
  unsigned int u = __float_as_uint(f);
  return (unsigned short)((u + 0x7FFFu + ((u >> 16) & 1u)) >> 16);
}
__device__ inline float bf2f(unsigned short h) {
  return __uint_as_float(((unsigned int)h) << 16);
}
__device__ inline bf16x8 lds_frag(const unsigned short* p) {  // p 8B-aligned
  bf16x4 a = *(const bf16x4*)p;
  bf16x4 c = *(const bf16x4*)(p + 4);
  return __builtin_shufflevector(a, c, 0, 1, 2, 3, 4, 5, 6, 7);
}

// ---------------------------------------------------------------------------
// Weight conversion: fp32 -> bf16 (hi/lo for theta & phi; hi for g, o).
// ---------------------------------------------------------------------------
__global__ __launch_bounds__(256)
void conv_weights(const float* __restrict__ wt, const float* __restrict__ wp,
                  const float* __restrict__ wg, const float* __restrict__ wo,
                  unsigned short* __restrict__ wth, unsigned short* __restrict__ wtl,
                  unsigned short* __restrict__ wph, unsigned short* __restrict__ wpl,
                  unsigned short* __restrict__ wgh, unsigned short* __restrict__ woh) {
  const int i = blockIdx.x * 256 + threadIdx.x;   // grid covers 131072
  if (i < 32768) {
    float a = wt[i];
    unsigned short h = f2bf(a);
    wth[i] = h; wtl[i] = f2bf(a - bf2f(h));
    float p = wp[i];
    h = f2bf(p);
    wph[i] = h; wpl[i] = f2bf(p - bf2f(h));
  }
  wgh[i] = f2bf(wg[i]);
  woh[i] = f2bf(wo[i]);
}

// ---------------------------------------------------------------------------
// Unified projection GEMM (MFMA). Rows stacked: mt=0 theta, mt=1 phi,
// mt=2..5 g. theta/phi use 3-term hi/lo (wh*xh + wl*xh + wh*xl) = fp32-level
// accuracy; g rows 1-term bf16. x is staged+transposed to LDS bf16 per
// 32-K chunk. Epilogues: theta -> thetaT[b][pos][hi(64)|lo(64)] via LDS
// transpose; phi -> fp32 pre; g -> bf16 pre.
// Grid (16 n-tiles, 6 m-tiles, 8 batches), 256 threads.
// ---------------------------------------------------------------------------
__global__ __launch_bounds__(256)
void proj_mfma(const unsigned short* __restrict__ wth, const unsigned short* __restrict__ wtl,
               const unsigned short* __restrict__ wph, const unsigned short* __restrict__ wpl,
               const unsigned short* __restrict__ wgh,
               const float* __restrict__ X,
               unsigned short* __restrict__ thetaT,
               float* __restrict__ phi_pre,
               unsigned short* __restrict__ g_pre) {
  // [plane hi/lo][pos 256][k 32 + pad] — stride 44: 8B-aligned rows, spread banks
  __shared__ __align__(16) unsigned short Bsh[2][256][44];
  const int b = blockIdx.z;
  const int mt = blockIdx.y;
  const int n0 = blockIdx.x * 256;
  const int tid = threadIdx.x;
  const int w = tid >> 6, l = tid & 63;
  const int l15 = l & 15, quad = l >> 4;
  const bool is_tp = (mt < 2);
  const unsigned short* Ah = (mt == 0) ? wth : (mt == 1) ? wph
                              : wgh + (size_t)(mt - 2) * 64 * 512;
  const unsigned short* Al = (mt == 0) ? wtl : wpl;  // only used when is_tp
  const float* Xb = X + (size_t)b * CC * CN;
  const int kpair = tid >> 4;   // 0..15 -> k rows 2*kpair, 2*kpair+1
  const int pcol = tid & 15;
  f32x4 acc[4][4] = {};

  for (int k0 = 0; k0 < CC; k0 += 32) {
    __syncthreads();  // previous chunk's frag reads done
    // ---- stage x[k0..k0+32)[n0..n0+256) transposed into LDS ----
#pragma unroll
    for (int it = 0; it < 4; ++it) {
      const int pl = (pcol + it * 16) * 4;  // 0..252
      const float4 u = *(const float4*)&Xb[(size_t)(k0 + 2 * kpair) * CN + n0 + pl];
      const float4 v = *(const float4*)&Xb[(size_t)(k0 + 2 * kpair + 1) * CN + n0 + pl];
      const float uu[4] = {u.x, u.y, u.z, u.w};
      const float vv[4] = {v.x, v.y, v.z, v.w};
#pragma unroll
      for (int e = 0; e < 4; ++e) {
        unsigned short h0 = f2bf(uu[e]), h1 = f2bf(vv[e]);
        ushort2 th; th.x = h0; th.y = h1;
        *(ushort2*)&Bsh[0][pl + e][2 * kpair] = th;
        if (is_tp) {
          ushort2 tl;
          tl.x = f2bf(uu[e] - bf2f(h0));
          tl.y = f2bf(vv[e] - bf2f(h1));
          *(ushort2*)&Bsh[1][pl + e][2 * kpair] = tl;
        }
      }
    }
    __syncthreads();
    // ---- MFMA ----
    bf16x8 ah[4], bh[4];
#pragma unroll
    for (int i = 0; i < 4; ++i)
      ah[i] = *(const bf16x8*)&Ah[(size_t)(i * 16 + l15) * 512 + k0 + quad * 8];
#pragma unroll
    for (int j = 0; j < 4; ++j)
      bh[j] = lds_frag(&Bsh[0][w * 64 + j * 16 + l15][quad * 8]);
#pragma unroll
    for (int i = 0; i < 4; ++i)
#pragma unroll
      for (int j = 0; j < 4; ++j)
        acc[i][j] = __builtin_amdgcn_mfma_f32_16x16x32_bf16(ah[i], bh[j], acc[i][j], 0, 0, 0);
    if (is_tp) {
      bf16x8 al[4], bl[4];
#pragma unroll
      for (int i = 0; i < 4; ++i)
        al[i] = *(const bf16x8*)&Al[(size_t)(i * 16 + l15) * 512 + k0 + quad * 8];
#pragma unroll
      for (int j = 0; j < 4; ++j)
        bl[j] = lds_frag(&Bsh[1][w * 64 + j * 16 + l15][quad * 8]);
#pragma unroll
      for (int i = 0; i < 4; ++i)
#pragma unroll
        for (int j = 0; j < 4; ++j) {
          acc[i][j] = __builtin_amdgcn_mfma_f32_16x16x32_bf16(al[i], bh[j], acc[i][j], 0, 0, 0);
          acc[i][j] = __builtin_amdgcn_mfma_f32_16x16x32_bf16(ah[i], bl[j], acc[i][j], 0, 0, 0);
        }
    }
  }

  if (mt == 0) {
    // theta: LDS-transpose epilogue -> thetaT[b][pos][128] (hi|lo), coalesced
    __syncthreads();
    unsigned short (*LT)[132] = (unsigned short (*)[132])Bsh;  // [128][132]
    unsigned short* Yb = thetaT + (size_t)b * CN * 128;
    for (int h = 0; h < 2; ++h) {
      if ((w >> 1) == h) {
#pragma unroll
        for (int i = 0; i < 4; ++i)
#pragma unroll
          for (int j = 0; j < 4; ++j)
#pragma unroll
            for (int r = 0; r < 4; ++r) {
              const int oc = i * 16 + quad * 4 + r;
              const int pl = (w & 1) * 64 + j * 16 + l15;  // 0..127
              const float v = acc[i][j][r];
              const unsigned short hi = f2bf(v);
              LT[pl][oc] = hi;
              LT[pl][64 + oc] = f2bf(v - bf2f(hi));
            }
      }
      __syncthreads();
#pragma unroll
      for (int it = 0; it < 16; ++it) {
        const int f = it * 256 + tid;       // [pos 128][c4 32]
        const int pl = f >> 5, c4 = (f & 31) * 4;
        const ushort4 v = *(const ushort4*)&LT[pl][c4];
        *(ushort4*)&Yb[(size_t)(n0 + h * 128 + pl) * 128 + c4] = v;
      }
      __syncthreads();
    }
  } else if (mt == 1) {
    float* Yb = phi_pre + (size_t)b * C8 * CN;
#pragma unroll
    for (int i = 0; i < 4; ++i)
#pragma unroll
      for (int j = 0; j < 4; ++j)
#pragma unroll
        for (int r = 0; r < 4; ++r) {
          const int oc = i * 16 + quad * 4 + r;
          const int pos = n0 + w * 64 + j * 16 + l15;
          Yb[(size_t)oc * CN + pos] = acc[i][j][r];
        }
  } else {
    unsigned short* Yb = g_pre + (size_t)b * C2 * CN;
#pragma unroll
    for (int i = 0; i < 4; ++i)
#pragma unroll
      for (int j = 0; j < 4; ++j)
#pragma unroll
        for (int r = 0; r < 4; ++r) {
          const int oc = (mt - 2) * 64 + i * 16 + quad * 4 + r;
          const int pos = n0 + w * 64 + j * 16 + l15;
          Yb[(size_t)oc * CN + pos] = f2bf(acc[i][j][r]);
        }
  }
}

// ---------------------------------------------------------------------------
// 2x2 maxpool + transpose -> phiT[b][m][128] bf16 (hi|lo).  grid (32,2,8)
// ---------------------------------------------------------------------------
__global__ __launch_bounds__(256)
void pool_phi_k(const float* __restrict__ pre, unsigned short* __restrict__ phiT) {
  __shared__ float raw[32][129];
  const int b = blockIdx.z, c0 = blockIdx.y * 32, h2 = blockIdx.x;
  const float* p = pre + ((size_t)b * C8 + c0) * CN + h2 * 128;
  const int tid = threadIdx.x;
#pragma unroll
  for (int it = 0; it < 16; ++it) {
    int e = tid + 256 * it;
    int r = e >> 7, col = e & 127;
    raw[r][col] = p[(size_t)r * CN + col];
  }
  __syncthreads();
  unsigned short* outB = phiT + ((size_t)b * CM + h2 * 32) * 128;
#pragma unroll
  for (int it = 0; it < 4; ++it) {
    int e = tid + 256 * it;
    int r = e & 31, w2 = e >> 5;
    float v = fmaxf(fmaxf(raw[r][2 * w2], raw[r][2 * w2 + 1]),
                    fmaxf(raw[r][64 + 2 * w2], raw[r][65 + 2 * w2]));
    unsigned short hi = f2bf(v);
    outB[(size_t)w2 * 128 + c0 + r] = hi;
    outB[(size_t)w2 * 128 + 64 + c0 + r] = f2bf(v - bf2f(hi));
  }
}

// ---------------------------------------------------------------------------
// 2x2 maxpool (bf16 in/out): g_pre[b][c2][n] -> gbf[b][c2][m].  grid (32,8,8)
// ---------------------------------------------------------------------------
__global__ __launch_bounds__(256)
void pool_g_bf(const unsigned short* __restrict__ pre, unsigned short* __restrict__ gbf) {
  __shared__ unsigned short raw[32][130];
  const int b = blockIdx.z, c0 = blockIdx.y * 32, h2 = blockIdx.x;
  const unsigned short* p = pre + ((size_t)b * C2 + c0) * CN + h2 * 128;
  const int tid = threadIdx.x;
#pragma unroll
  for (int it = 0; it < 16; ++it) {
    int e = tid + 256 * it;
    int r = e >> 7, col = e & 127;
    raw[r][col] = p[(size_t)r * CN + col];
  }
  __syncthreads();
#pragma unroll
  for (int it = 0; it < 4; ++it) {
    int e = tid + 256 * it;
    int w2 = e & 31, r = e >> 5;
    float v = fmaxf(fmaxf(bf2f(raw[r][2 * w2]), bf2f(raw[r][2 * w2 + 1])),
                    fmaxf(bf2f(raw[r][64 + 2 * w2]), bf2f(raw[r][65 + 2 * w2])));
    gbf[((size_t)b * C2 + c0 + r) * CM + h2 * 32 + w2] = f2bf(v);
  }
}

// ---------------------------------------------------------------------------
// MFMA flash attention (unchanged from R2 except bf16 output [b][q][c2]).
// ---------------------------------------------------------------------------
__global__ __launch_bounds__(256)
void attn_mfma(const unsigned short* __restrict__ thetaT,
               const unsigned short* __restrict__ phiT,
               const unsigned short* __restrict__ gbf,
               unsigned short* __restrict__ attbf) {
  __shared__ __align__(16) unsigned short P2[2][2][4][16][8];
  const int b = blockIdx.y;
  const int q0 = blockIdx.x * 32;
  const int tid = threadIdx.x;
  const int w = tid >> 6, l = tid & 63;
  const int l15 = l & 15, quad = l >> 4;
  const int subq = w & 1, subj = w >> 1;

  const unsigned short* trow =
      thetaT + (size_t)(b * CN + q0 + subq * 16 + l15) * 128;
  const bf16x8 ah0 = *(const bf16x8*)(trow + quad * 8);
  const bf16x8 ah1 = *(const bf16x8*)(trow + 32 + quad * 8);
  const bf16x8 al0 = *(const bf16x8*)(trow + 64 + quad * 8);
  const bf16x8 al1 = *(const bf16x8*)(trow + 96 + quad * 8);

  f32x4 acc[2][4] = {};
  float dn0 = 0.f, dn1 = 0.f;
  const unsigned short* phB = phiT + (size_t)b * CM * 128;
  const unsigned short* gB = gbf + (size_t)b * C2 * CM;
  const int jl = subj * 16 + l15;
  const int kq = jl >> 3, el = jl & 7;

  for (int j0 = 0; j0 < CM; j0 += 32) {
    const int buf = (j0 >> 5) & 1;
    const unsigned short* prow = phB + (size_t)(j0 + jl) * 128;
    const bf16x8 bh0 = *(const bf16x8*)(prow + quad * 8);
    const bf16x8 bh1 = *(const bf16x8*)(prow + 32 + quad * 8);
    const bf16x8 bl0 = *(const bf16x8*)(prow + 64 + quad * 8);
    const bf16x8 bl1 = *(const bf16x8*)(prow + 96 + quad * 8);
    f32x4 S = {0.f, 0.f, 0.f, 0.f};
    S = __builtin_amdgcn_mfma_f32_16x16x32_bf16(ah0, bh0, S, 0, 0, 0);
    S = __builtin_amdgcn_mfma_f32_16x16x32_bf16(ah1, bh1, S, 0, 0, 0);
    S = __builtin_amdgcn_mfma_f32_16x16x32_bf16(al0, bh0, S, 0, 0, 0);
    S = __builtin_amdgcn_mfma_f32_16x16x32_bf16(al1, bh1, S, 0, 0, 0);
    S = __builtin_amdgcn_mfma_f32_16x16x32_bf16(ah0, bl0, S, 0, 0, 0);
    S = __builtin_amdgcn_mfma_f32_16x16x32_bf16(ah1, bl1, S, 0, 0, 0);
#pragma unroll
    for (int r = 0; r < 4; ++r)
      P2[buf][subq][kq][quad * 4 + r][el] = f2bf(__expf(S[r]));
    __syncthreads();
    const bf16x8 pa0 = *(const bf16x8*)&P2[buf][0][quad][l15][0];
    const bf16x8 pa1 = *(const bf16x8*)&P2[buf][1][quad][l15][0];
    float s0 = 0.f, s1 = 0.f;
#pragma unroll
    for (int e = 0; e < 8; ++e) {
      s0 += bf2f((unsigned short)pa0[e]);
      s1 += bf2f((unsigned short)pa1[e]);
    }
    s0 += __shfl_xor(s0, 16); s0 += __shfl_xor(s0, 32);
    s1 += __shfl_xor(s1, 16); s1 += __shfl_xor(s1, 32);
    dn0 += s0; dn1 += s1;
#pragma unroll
    for (int ct = 0; ct < 4; ++ct) {
      const unsigned short* grow =
          gB + (size_t)(w * 64 + ct * 16 + l15) * CM + j0 + quad * 8;
      const bf16x8 gb = *(const bf16x8*)grow;
      acc[0][ct] = __builtin_amdgcn_mfma_f32_16x16x32_bf16(pa0, gb, acc[0][ct], 0, 0, 0);
      acc[1][ct] = __builtin_amdgcn_mfma_f32_16x16x32_bf16(pa1, gb, acc[1][ct], 0, 0, 0);
    }
  }
  const float inv0 = 1.0f / dn0;
  const float inv1 = 1.0f / dn1;
  unsigned short* attB = attbf + ((size_t)b * CN + q0) * C2;
#pragma unroll
  for (int r = 0; r < 4; ++r) {
    const int qc = quad * 4 + r;
    const float i0 = __shfl(inv0, qc);
    const float i1 = __shfl(inv1, qc);
#pragma unroll
    for (int ct = 0; ct < 4; ++ct) {
      const int col = w * 64 + ct * 16 + l15;
      attB[(size_t)qc * C2 + col] = f2bf(acc[0][ct][r] * i0);
      attB[(size_t)(16 + qc) * C2 + col] = f2bf(acc[1][ct][r] * i1);
    }
  }
}

// ---------------------------------------------------------------------------
// Output projection (MFMA, streaming, no LDS): out = x + gamma * (Wo @ att).
// A = woh [512][256], B = attbf [b][pos][256]. Grid (16 nt, 8 mt, 8 b).
// ---------------------------------------------------------------------------
__global__ __launch_bounds__(256)
void oproj_mfma(const unsigned short* __restrict__ woh,
                const unsigned short* __restrict__ attbf,
                const float* __restrict__ X, const float* __restrict__ gamma,
                float* __restrict__ out) {
  const int b = blockIdx.z;
  const int mt = blockIdx.y;
  const int n0 = blockIdx.x * 256;
  const int tid = threadIdx.x;
  const int w = tid >> 6, l = tid & 63;
  const int l15 = l & 15, quad = l >> 4;
  const unsigned short* Bb = attbf + (size_t)b * CN * C2;
  f32x4 acc[4][4] = {};
  for (int k0 = 0; k0 < C2; k0 += 32) {
    bf16x8 a[4], bb[4];
#pragma unroll
    for (int i = 0; i < 4; ++i)
      a[i] = *(const bf16x8*)&woh[(size_t)(mt * 64 + i * 16 + l15) * C2 + k0 + quad * 8];
#pragma unroll
    for (int j = 0; j < 4; ++j)
      bb[j] = *(const bf16x8*)&Bb[(size_t)(n0 + w * 64 + j * 16 + l15) * C2 + k0 + quad * 8];
#pragma unroll
    for (int i = 0; i < 4; ++i)
#pragma unroll
      for (int j = 0; j < 4; ++j)
        acc[i][j] = __builtin_amdgcn_mfma_f32_16x16x32_bf16(a[i], bb[j], acc[i][j], 0, 0, 0);
  }
  const float gm = gamma[0];
#pragma unroll
  for (int i = 0; i < 4; ++i)
#pragma unroll
    for (int j = 0; j < 4; ++j)
#pragma unroll
      for (int r = 0; r < 4; ++r) {
        const int c = mt * 64 + i * 16 + quad * 4 + r;
        const int pos = n0 + w * 64 + j * 16 + l15;
        const size_t idx = ((size_t)b * CC + c) * CN + pos;
        out[idx] = X[idx] + gm * acc[i][j][r];
      }
}

// ---------------------------------------------------------------------------
extern "C" void kernel_launch(void* const* d_in, const int* in_sizes, int n_in,
                              void* d_out, int out_size, void* d_ws, size_t ws_size,
                              hipStream_t stream) {
  const float* x       = (const float*)d_in[0];
  const float* w_theta = (const float*)d_in[1];
  const float* w_phi   = (const float*)d_in[2];
  const float* w_g     = (const float*)d_in[3];
  const float* w_o     = (const float*)d_in[4];
  const float* gamma   = (const float*)d_in[5];
  float* out = (float*)d_out;
  char* wsb = (char*)d_ws;

  // Workspace layout (bytes), total 40,632,320 (<= 48 MiB proven safe):
  unsigned short* thetaT  = (unsigned short*)(wsb + 0);         //  8 MiB [B,4096,128]
  unsigned short* phiT    = (unsigned short*)(wsb + 8388608);   //  2 MiB [B,1024,128]
  unsigned short* gbf     = (unsigned short*)(wsb + 10485760);  //  4 MiB [B,256,1024]
  float*          phi_pre = (float*)(wsb + 14680064);           //  8 MiB [B,64,4096]
  unsigned short* g_pre   = (unsigned short*)(wsb + 23068672);  // 16 MiB [B,256,4096]
  unsigned short* attbf   = (unsigned short*)(wsb + 23068672);  // aliases g_pre (dead)
  unsigned short* wth     = (unsigned short*)(wsb + 39845888);
  unsigned short* wtl     = (unsigned short*)(wsb + 39911424);
  unsigned short* wph     = (unsigned short*)(wsb + 39976960);
  unsigned short* wpl     = (unsigned short*)(wsb + 40042496);
  unsigned short* wgh     = (unsigned short*)(wsb + 40108032);
  unsigned short* woh     = (unsigned short*)(wsb + 40370176);

  dim3 blk(256);
  conv_weights<<<512, blk, 0, stream>>>(w_theta, w_phi, w_g, w_o,
                                        wth, wtl, wph, wpl, wgh, woh);
  proj_mfma<<<dim3(16, 6, CB), blk, 0, stream>>>(wth, wtl, wph, wpl, wgh,
                                                 x, thetaT, phi_pre, g_pre);
  pool_phi_k<<<dim3(32, 2, CB), blk, 0, stream>>>(phi_pre, phiT);
  pool_g_bf<<<dim3(32, 8, CB), blk, 0, stream>>>(g_pre, gbf);
  attn_mfma<<<dim3(128, CB), blk, 0, stream>>>(thetaT, phiT, gbf, attbf);
  oproj_mfma<<<dim3(16, 8, CB), blk, 0, stream>>>(woh, attbf, x, gamma, out);
}

// Round 5
// 343.623 us; speedup vs baseline: 2.4137x; 1.1784x over previous
//
#include <hip/hip_runtime.h>
#include <math.h>

// Problem constants (B=8, C=512, H=W=64)
constexpr int CB = 8;
constexpr int CC = 512;
constexpr int CN = 4096;   // H*W
constexpr int CM = 1024;   // pooled positions
constexpr int C8 = 64;     // C/8
constexpr int C2 = 256;    // C/2

typedef __attribute__((ext_vector_type(8))) short short8;
typedef __attribute__((ext_vector_type(8))) _Float16 half8;
typedef __attribute__((ext_vector_type(4))) float f32x4;

__device__ inline unsigned short f2bf(float f) {
  unsigned int u = __float_as_uint(f);
  return (unsigned short)((u + 0x7FFFu + ((u >> 16) & 1u)) >> 16);
}
__device__ inline unsigned short f16bits(float f) {
  union { _Float16 h; unsigned short u; } c;
  c.h = (_Float16)f;
  return c.u;
}

// ---------------------------------------------------------------------------
// Weight conversion: theta/phi -> f16 hi/lo (2-term), g -> f16, o -> bf16.
// ---------------------------------------------------------------------------
__global__ __launch_bounds__(256)
void conv_w(const float* __restrict__ wt, const float* __restrict__ wp,
            const float* __restrict__ wg, const float* __restrict__ wo,
            _Float16* __restrict__ wth, _Float16* __restrict__ wtl,
            _Float16* __restrict__ wph, _Float16* __restrict__ wpl,
            _Float16* __restrict__ wgf, unsigned short* __restrict__ woh) {
  const int i = blockIdx.x * 256 + threadIdx.x;
  if (i < 32768) {
    float a = wt[i];
    _Float16 h = (_Float16)a;
    wth[i] = h; wtl[i] = (_Float16)(a - (float)h);
    a = wp[i];
    h = (_Float16)a;
    wph[i] = h; wpl[i] = (_Float16)(a - (float)h);
  }
  wgf[i] = (_Float16)wg[i];
  woh[i] = f2bf(wo[i]);
}

// ---------------------------------------------------------------------------
// Transpose+convert: x fp32 [b][c][n] -> xT f16 [b][n][c].
// grid (64 n-tiles, 8 c-tiles, 8 b), 64x64 tiles.
// ---------------------------------------------------------------------------
__global__ __launch_bounds__(256)
void xpose(const float* __restrict__ X, _Float16* __restrict__ xT) {
  __shared__ __align__(16) float raw[64][68];
  const int b = blockIdx.z, c0 = blockIdx.y * 64, n0 = blockIdx.x * 64;
  const float* Xb = X + ((size_t)b * CC + c0) * CN + n0;
  const int tid = threadIdx.x;
#pragma unroll
  for (int it = 0; it < 4; ++it) {
    const int idx = it * 256 + tid;
    const int row = idx >> 4, col4 = (idx & 15) * 4;
    *(float4*)&raw[row][col4] = *(const float4*)&Xb[(size_t)row * CN + col4];
  }
  __syncthreads();
  unsigned short* Yb = (unsigned short*)(xT + ((size_t)b * CN + n0) * CC + c0);
#pragma unroll
  for (int it = 0; it < 4; ++it) {
    const int idx = it * 256 + tid;
    const int n = idx >> 4, c4 = (idx & 15) * 4;
    ushort4 o;
    o.x = f16bits(raw[c4 + 0][n]);
    o.y = f16bits(raw[c4 + 1][n]);
    o.z = f16bits(raw[c4 + 2][n]);
    o.w = f16bits(raw[c4 + 3][n]);
    *(ushort4*)&Yb[(size_t)n * CC + c4] = o;
  }
}

// ---------------------------------------------------------------------------
// theta projection (streaming f16 MFMA, 2-term W hi/lo), output transposed
// thT[b][pos][64] f16 via LDS transpose epilogue. grid (64, 8).
// ---------------------------------------------------------------------------
__global__ __launch_bounds__(256)
void proj_th(const _Float16* __restrict__ Wh, const _Float16* __restrict__ Wl,
             const _Float16* __restrict__ xT, _Float16* __restrict__ thT) {
  __shared__ __align__(16) unsigned short LT[64][68];
  const int b = blockIdx.y, n0 = blockIdx.x * 64;
  const int tid = threadIdx.x;
  const int w = tid >> 6, l = tid & 63;
  const int l15 = l & 15, quad = l >> 4;
  f32x4 acc[4] = {};
  const _Float16* Brow = xT + (size_t)(b * CN + n0 + w * 16 + l15) * CC;
  for (int k0 = 0; k0 < CC; k0 += 32) {
    const half8 bfr = *(const half8*)&Brow[k0 + quad * 8];
#pragma unroll
    for (int i = 0; i < 4; ++i) {
      const half8 ah = *(const half8*)&Wh[(size_t)(i * 16 + l15) * CC + k0 + quad * 8];
      const half8 al = *(const half8*)&Wl[(size_t)(i * 16 + l15) * CC + k0 + quad * 8];
      acc[i] = __builtin_amdgcn_mfma_f32_16x16x32_f16(ah, bfr, acc[i], 0, 0, 0);
      acc[i] = __builtin_amdgcn_mfma_f32_16x16x32_f16(al, bfr, acc[i], 0, 0, 0);
    }
  }
#pragma unroll
  for (int i = 0; i < 4; ++i)
#pragma unroll
    for (int r = 0; r < 4; ++r)
      LT[w * 16 + l15][i * 16 + quad * 4 + r] = f16bits(acc[i][r]);
  __syncthreads();
  unsigned short* Yb = (unsigned short*)(thT + (size_t)(b * CN + n0) * C8);
#pragma unroll
  for (int it = 0; it < 4; ++it) {
    const int idx = it * 256 + tid;
    const int pos = idx >> 4, c4 = (idx & 15) * 4;
    ushort4 v = *(const ushort4*)&LT[pos][c4];
    *(ushort4*)&Yb[(size_t)pos * C8 + c4] = v;
  }
}

// ---------------------------------------------------------------------------
// phi + g projections with FUSED 2x2 maxpool epilogue.
// mt=0: phi (2-term) -> phT[b][m][64] f16; mt=1..4: g -> gbf[b][c2][m] bf16.
// Wave w = image row tile*4+w. shfl_xor(1) horizontal; LDS row-pair combine.
// grid (16, 5, 8).
// ---------------------------------------------------------------------------
__global__ __launch_bounds__(256)
void proj_pg(const _Float16* __restrict__ Wph, const _Float16* __restrict__ Wpl,
             const _Float16* __restrict__ Wg, const _Float16* __restrict__ xT,
             _Float16* __restrict__ phT, unsigned short* __restrict__ gbf) {
  __shared__ float Pbuf[2][64][33];
  const int b = blockIdx.z, mt = blockIdx.y, tile = blockIdx.x;
  const int n0 = tile * 256;
  const int tid = threadIdx.x;
  const int w = tid >> 6, l = tid & 63;
  const int l15 = l & 15, quad = l >> 4;
  const bool isphi = (mt == 0);
  const _Float16* Ah = isphi ? Wph : (Wg + (size_t)(mt - 1) * 64 * CC);
  f32x4 acc[4][4] = {};
  const _Float16* Bbase = xT + (size_t)(b * CN + n0 + w * 64) * CC;
  for (int k0 = 0; k0 < CC; k0 += 32) {
    half8 bf[4], ah[4];
#pragma unroll
    for (int j = 0; j < 4; ++j)
      bf[j] = *(const half8*)&Bbase[(size_t)(j * 16 + l15) * CC + k0 + quad * 8];
#pragma unroll
    for (int i = 0; i < 4; ++i)
      ah[i] = *(const half8*)&Ah[(size_t)(i * 16 + l15) * CC + k0 + quad * 8];
#pragma unroll
    for (int i = 0; i < 4; ++i)
#pragma unroll
      for (int j = 0; j < 4; ++j)
        acc[i][j] = __builtin_amdgcn_mfma_f32_16x16x32_f16(ah[i], bf[j], acc[i][j], 0, 0, 0);
    if (isphi) {
      half8 al[4];
#pragma unroll
      for (int i = 0; i < 4; ++i)
        al[i] = *(const half8*)&Wpl[(size_t)(i * 16 + l15) * CC + k0 + quad * 8];
#pragma unroll
      for (int i = 0; i < 4; ++i)
#pragma unroll
        for (int j = 0; j < 4; ++j)
          acc[i][j] = __builtin_amdgcn_mfma_f32_16x16x32_f16(al[i], bf[j], acc[i][j], 0, 0, 0);
    }
  }
  // ---- pooled epilogue ----
  const bool owner = ((l15 & 1) == 0);
  const int colh = l15 >> 1;
  if (w & 1) {
#pragma unroll
    for (int i = 0; i < 4; ++i)
#pragma unroll
      for (int j = 0; j < 4; ++j)
#pragma unroll
        for (int r = 0; r < 4; ++r) {
          float v = acc[i][j][r];
          float o = __shfl_xor(v, 1);
          v = fmaxf(v, o);
          if (owner) Pbuf[w >> 1][i * 16 + quad * 4 + r][j * 8 + colh] = v;
        }
  }
  __syncthreads();
  if (!(w & 1)) {
    const int pr = tile * 2 + (w >> 1);
    unsigned short* phB = (unsigned short*)(phT + ((size_t)b * CM + pr * 32) * C8);
#pragma unroll
    for (int i = 0; i < 4; ++i)
#pragma unroll
      for (int j = 0; j < 4; ++j)
#pragma unroll
        for (int r = 0; r < 4; ++r) {
          float v = acc[i][j][r];
          float o = __shfl_xor(v, 1);
          v = fmaxf(v, o);
          if (owner) {
            const int oc = i * 16 + quad * 4 + r;
            const int col = j * 8 + colh;
            v = fmaxf(v, Pbuf[w >> 1][oc][col]);
            if (isphi)
              phB[(size_t)col * C8 + oc] = f16bits(v);
            else
              gbf[((size_t)b * C2 + (mt - 1) * 64 + oc) * CM + pr * 32 + col] = f2bf(v);
          }
        }
  }
}

// ---------------------------------------------------------------------------
// Fused attention v3b — no barriers. Block = 64 queries x batch; 4 waves
// split c2 (64 cols each); each wave computes the full S^T redundantly.
// S^T = mfma(A=phi, B=theta) f16 -> exp -> PER-WAVE LDS round-trip into
// PV A-layout (row q, 32 j contiguous; pad 40 keeps 16B align) -> PV mfma.
// Wave-internal LDS write->read needs only lgkmcnt (compiler), no syncs.
// grid (64, 8).
// ---------------------------------------------------------------------------
__global__ __launch_bounds__(256)
void attn_v3(const _Float16* __restrict__ thT, const _Float16* __restrict__ phT,
             const unsigned short* __restrict__ gbf,
             unsigned short* __restrict__ attbf) {
  __shared__ __align__(16) unsigned short Pl[4][4][16][40]; // [wave][qs][q][j+pad]
  const int b = blockIdx.y;
  const int q0 = blockIdx.x * 64;
  const int tid = threadIdx.x;
  const int w = tid >> 6, l = tid & 63;
  const int l15 = l & 15, quad = l >> 4;
  // theta B-frags (resident): 4 q-subtiles x 2 K-chunks
  half8 tb[4][2];
#pragma unroll
  for (int qs = 0; qs < 4; ++qs)
#pragma unroll
    for (int kc = 0; kc < 2; ++kc)
      tb[qs][kc] = *(const half8*)&thT[(size_t)(b * CN + q0 + qs * 16 + l15) * C8 +
                                       kc * 32 + quad * 8];
  f32x4 acc[4][4] = {};   // [qs][ct], wave's c2 = w*64 + ct*16 + l15
  float dnp[4] = {0.f, 0.f, 0.f, 0.f};
  const _Float16* phB = phT + (size_t)b * CM * C8;
  const unsigned short* gB = gbf + (size_t)b * C2 * CM;

  for (int j0 = 0; j0 < CM; j0 += 32) {
    half8 pa[2][2];
#pragma unroll
    for (int jt = 0; jt < 2; ++jt)
#pragma unroll
      for (int kc = 0; kc < 2; ++kc)
        pa[jt][kc] = *(const half8*)&phB[(size_t)(j0 + jt * 16 + l15) * C8 +
                                         kc * 32 + quad * 8];
    // S^T, exp, write in PV-A layout. Thread (l15=q, quad) holds
    // j = jt*16 + quad*4 + r  ->  Pl[w][qs][l15][jt*16 + quad*4 .. +3]
#pragma unroll
    for (int qs = 0; qs < 4; ++qs) {
      f32x4 S0 = {0.f, 0.f, 0.f, 0.f}, S1 = {0.f, 0.f, 0.f, 0.f};
      S0 = __builtin_amdgcn_mfma_f32_16x16x32_f16(pa[0][0], tb[qs][0], S0, 0, 0, 0);
      S0 = __builtin_amdgcn_mfma_f32_16x16x32_f16(pa[0][1], tb[qs][1], S0, 0, 0, 0);
      S1 = __builtin_amdgcn_mfma_f32_16x16x32_f16(pa[1][0], tb[qs][0], S1, 0, 0, 0);
      S1 = __builtin_amdgcn_mfma_f32_16x16x32_f16(pa[1][1], tb[qs][1], S1, 0, 0, 0);
      float e0[4], e1[4];
#pragma unroll
      for (int r = 0; r < 4; ++r) { e0[r] = __expf(S0[r]); e1[r] = __expf(S1[r]); }
      dnp[qs] += (e0[0] + e0[1]) + (e0[2] + e0[3]) +
                 (e1[0] + e1[1]) + (e1[2] + e1[3]);
      ushort4 w0, w1;
      w0.x = f2bf(e0[0]); w0.y = f2bf(e0[1]); w0.z = f2bf(e0[2]); w0.w = f2bf(e0[3]);
      w1.x = f2bf(e1[0]); w1.y = f2bf(e1[1]); w1.z = f2bf(e1[2]); w1.w = f2bf(e1[3]);
      *(ushort4*)&Pl[w][qs][l15][quad * 4] = w0;
      *(ushort4*)&Pl[w][qs][l15][16 + quad * 4] = w1;
    }
    // read back PV A-frags (A[m=l15][k=quad*8..+7]) — wave-local, no barrier
    short8 pfrag[4];
#pragma unroll
    for (int qs = 0; qs < 4; ++qs)
      pfrag[qs] = *(const short8*)&Pl[w][qs][l15][quad * 8];
#pragma unroll
    for (int ct = 0; ct < 4; ++ct) {
      const short8 gf = *(const short8*)&gB[(size_t)(w * 64 + ct * 16 + l15) * CM +
                                            j0 + quad * 8];
#pragma unroll
      for (int qs = 0; qs < 4; ++qs)
        acc[qs][ct] = __builtin_amdgcn_mfma_f32_16x16x32_bf16(pfrag[qs], gf,
                                                              acc[qs][ct], 0, 0, 0);
    }
  }
  // denominators + store
  unsigned short* attB = attbf + (size_t)(b * CN + q0) * C2;
#pragma unroll
  for (int qs = 0; qs < 4; ++qs) {
    float d = dnp[qs];
    d += __shfl_xor(d, 16);
    d += __shfl_xor(d, 32);
    const float inv = 1.0f / d;        // valid for q = l15 (all lanes)
#pragma unroll
    for (int r = 0; r < 4; ++r) {
      const float iv = __shfl(inv, quad * 4 + r);
      const int row = qs * 16 + quad * 4 + r;
#pragma unroll
      for (int ct = 0; ct < 4; ++ct)
        attB[(size_t)row * C2 + w * 64 + ct * 16 + l15] =
            f2bf(acc[qs][ct][r] * iv);
    }
  }
}

// ---------------------------------------------------------------------------
// Output projection (MFMA, streaming): out = x + gamma * (Wo @ att).
// A = woh [512][256] bf16, B = attbf [b][pos][256] bf16. Grid (16, 8, 8).
// ---------------------------------------------------------------------------
__global__ __launch_bounds__(256)
void oproj_mfma(const unsigned short* __restrict__ woh,
                const unsigned short* __restrict__ attbf,
                const float* __restrict__ X, const float* __restrict__ gamma,
                float* __restrict__ out) {
  const int b = blockIdx.z;
  const int mt = blockIdx.y;
  const int n0 = blockIdx.x * 256;
  const int tid = threadIdx.x;
  const int w = tid >> 6, l = tid & 63;
  const int l15 = l & 15, quad = l >> 4;
  const unsigned short* Bb = attbf + (size_t)b * CN * C2;
  f32x4 acc[4][4] = {};
  for (int k0 = 0; k0 < C2; k0 += 32) {
    short8 a[4], bb[4];
#pragma unroll
    for (int i = 0; i < 4; ++i)
      a[i] = *(const short8*)&woh[(size_t)(mt * 64 + i * 16 + l15) * C2 + k0 + quad * 8];
#pragma unroll
    for (int j = 0; j < 4; ++j)
      bb[j] = *(const short8*)&Bb[(size_t)(n0 + w * 64 + j * 16 + l15) * C2 + k0 + quad * 8];
#pragma unroll
    for (int i = 0; i < 4; ++i)
#pragma unroll
      for (int j = 0; j < 4; ++j)
        acc[i][j] = __builtin_amdgcn_mfma_f32_16x16x32_bf16(a[i], bb[j], acc[i][j], 0, 0, 0);
  }
  const float gm = gamma[0];
#pragma unroll
  for (int i = 0; i < 4; ++i)
#pragma unroll
    for (int j = 0; j < 4; ++j)
#pragma unroll
      for (int r = 0; r < 4; ++r) {
        const int c = mt * 64 + i * 16 + quad * 4 + r;
        const int pos = n0 + w * 64 + j * 16 + l15;
        const size_t idx = ((size_t)b * CC + c) * CN + pos;
        out[idx] = X[idx] + gm * acc[i][j][r];
      }
}

// ---------------------------------------------------------------------------
extern "C" void kernel_launch(void* const* d_in, const int* in_sizes, int n_in,
                              void* d_out, int out_size, void* d_ws, size_t ws_size,
                              hipStream_t stream) {
  const float* x       = (const float*)d_in[0];
  const float* w_theta = (const float*)d_in[1];
  const float* w_phi   = (const float*)d_in[2];
  const float* w_g     = (const float*)d_in[3];
  const float* w_o     = (const float*)d_in[4];
  const float* gamma   = (const float*)d_in[5];
  float* out = (float*)d_out;
  char* wsb = (char*)d_ws;

  // Workspace layout (bytes), total 43,778,048:
  _Float16*       xT    = (_Float16*)(wsb + 0);          // 32 MiB [B,4096,512]
  _Float16*       thT   = (_Float16*)(wsb + 33554432);   //  4 MiB [B,4096,64]
  _Float16*       phT   = (_Float16*)(wsb + 37748736);   //  1 MiB [B,1024,64]
  unsigned short* gbf   = (unsigned short*)(wsb + 38797312); // 4 MiB [B,256,1024]
  _Float16*       wth   = (_Float16*)(wsb + 42991616);
  _Float16*       wtl   = (_Float16*)(wsb + 43057152);
  _Float16*       wph   = (_Float16*)(wsb + 43122688);
  _Float16*       wpl   = (_Float16*)(wsb + 43188224);
  _Float16*       wgf   = (_Float16*)(wsb + 43253760);
  unsigned short* woh   = (unsigned short*)(wsb + 43515904);
  unsigned short* attbf = (unsigned short*)(wsb + 0);    // 16 MiB, aliases xT (dead)

  dim3 blk(256);
  conv_w<<<512, blk, 0, stream>>>(w_theta, w_phi, w_g, w_o,
                                  wth, wtl, wph, wpl, wgf, woh);
  xpose<<<dim3(64, 8, CB), blk, 0, stream>>>(x, xT);
  proj_th<<<dim3(64, CB), blk, 0, stream>>>(wth, wtl, xT, thT);
  proj_pg<<<dim3(16, 5, CB), blk, 0, stream>>>(wph, wpl, wgf, xT, phT, gbf);
  attn_v3<<<dim3(64, CB), blk, 0, stream>>>(thT, phT, gbf, attbf);
  oproj_mfma<<<dim3(16, 8, CB), blk, 0, stream>>>(woh, attbf, x, gamma, out);
}